// Round 6
// baseline (2916.832 us; speedup 1.0000x reference)
//
#include <hip/hip_runtime.h>
#include <hip/hip_bf16.h>

#define DEVFN __device__ __forceinline__

// ---- workspace layout (bytes) ----
static constexpr size_t OFF_CTRS   = 0;                          // barrier arenas (zeroed): 4 arenas x 4096 ints = 64KB
static constexpr size_t OFF_STATS  = 131328;                     // 48 floats
static constexpr size_t OFF_EW     = 131584;                     // 4 floats
static constexpr size_t OFF_MASK32 = 131840;                     // 768 floats
static constexpr size_t OFF_EMB    = 135168;                     // 786,432 B
static constexpr size_t OFF_WPT    = 921600;                     // 8,388,608 B
static constexpr size_t OFF_BIAS   = 9310208;                    // 131,072 B
static constexpr size_t OFF_XW     = 9441280;                    // 50,331,648 B
static constexpr size_t OFF_OUT0   = 59772928;                   // 1,572,864 B
static constexpr size_t OFF_OUT1   = 61345792;                   // 1,572,864 B
static constexpr size_t OFF_Y      = 62918656;                   // 96*2*16384*4
static constexpr size_t OFF_H      = 75501568;                   // 97*2*2048*4

template<int BF>
DEVFN float ldin(const void* p, size_t i) {
  if (BF) {
    unsigned short u = ((const unsigned short*)p)[i];
    return __uint_as_float(((unsigned)u) << 16);
  }
  return ((const float*)p)[i];
}
DEVFN float ldraw(const void* p, size_t i, int bf) {
  if (bf) {
    unsigned short u = ((const unsigned short*)p)[i];
    return __uint_as_float(((unsigned)u) << 16);
  }
  return ((const float*)p)[i];
}

DEVFN float sigm(float x) { return 1.f / (1.f + __expf(-x)); }
DEVFN float clip3(float x) { return fminf(fmaxf(x, -3.f), 3.f); }

// dtype self-detection
DEVFN int detect_bf(const void* maskp) {
  return (((const unsigned*)maskp)[0] == 0x3F800000u) ? 0 : 1;
}

// ---------------- fused prep: convert + Wp transpose + embedding gather ----------------
// blocks [0,132): convert small tensors; [132,644): Wp transpose; [644,1412): gather
template<int BF>
__global__ void prep_k(const int* __restrict__ tokens, const void* __restrict__ maskp,
                       const void* __restrict__ et, const void* __restrict__ bias,
                       const void* __restrict__ ew, const void* __restrict__ gm,
                       const void* __restrict__ Wp,
                       float* bias32, float* mask32, float* ew32, float* emb, float* WpT) {
  if (detect_bf(maskp) != BF) return;
  const int bid = blockIdx.x, tid = threadIdx.x;

  if (bid < 132) {
    size_t i = (size_t)bid * 256 + tid;
    if (i >= 33540) return;
    if (i < 32768)       bias32[i] = ldin<BF>(bias, i);
    else if (i < 33536)  mask32[i - 32768] = ldin<BF>(maskp, i - 32768);
    else if (i < 33539)  ew32[i - 33536]   = ldin<BF>(ew, i - 33536);
    else                 ew32[3] = ldin<BF>(gm, 0);
    return;
  }

  if (bid < 644) {
    const int r = bid - 132;
    const int kt = r & 31, pt = (r >> 5) & 3, dl = r >> 7;
    __shared__ float tile[64][65];
    for (int it = 0; it < 4; ++it) {
      int lin = it * 1024 + tid * 4;
      int kk = lin >> 6, pp = lin & 63;
      size_t src = ((size_t)(dl * 2048 + kt * 64 + kk)) * 256 + pt * 64 + pp;
      float v0, v1, v2, v3;
      if (BF) {
        const unsigned short* sp = (const unsigned short*)Wp + src;
        v0 = __uint_as_float(((unsigned)sp[0]) << 16);
        v1 = __uint_as_float(((unsigned)sp[1]) << 16);
        v2 = __uint_as_float(((unsigned)sp[2]) << 16);
        v3 = __uint_as_float(((unsigned)sp[3]) << 16);
      } else {
        float4 v = *(const float4*)((const float*)Wp + src);
        v0 = v.x; v1 = v.y; v2 = v.z; v3 = v.w;
      }
      tile[pp + 0][kk] = v0; tile[pp + 1][kk] = v1; tile[pp + 2][kk] = v2; tile[pp + 3][kk] = v3;
    }
    __syncthreads();
    for (int it = 0; it < 4; ++it) {
      int lin = it * 1024 + tid * 4;
      int pr = lin >> 6, kc = lin & 63;
      float4 o;
      o.x = tile[pr][kc + 0]; o.y = tile[pr][kc + 1]; o.z = tile[pr][kc + 2]; o.w = tile[pr][kc + 3];
      *(float4*)(WpT + ((size_t)(dl * 256 + pt * 64 + pr)) * 2048 + kt * 64 + kc) = o;
    }
    return;
  }

  const int bt = bid - 644;
  const int tok = tokens[bt];
  emb[(size_t)bt * 256 + tid] = ldin<BF>(et, (size_t)tok * 256 + tid);
}

// ---------------- xW = x @ Wk[dl] + b[dl] ----------------
template<int BF>
__global__ __launch_bounds__(256) void xw_gemm_k(
    const void* __restrict__ maskp, const float* __restrict__ x_fwd, const float* __restrict__ x_bwd,
    const void* __restrict__ Wk, const float* __restrict__ bias32, float* __restrict__ xW, int layer) {
  if (detect_bf(maskp) != BF) return;
  const int nt = blockIdx.x, mt = blockIdx.y, dir = blockIdx.z;
  const int dl = dir * 2 + layer;
  const float* xb = dir ? x_bwd : x_fwd;
  const int tid = threadIdx.x;

  __shared__ float As[16][68];
  __shared__ float Bs[16][68];

  float acc[4][4] = {};
  const int tx = tid & 15, ty = tid >> 4;

  const int am = tid >> 2;
  const int ak = (tid & 3) * 4;
  const int m_glob = mt * 64 + am;
  const int t_ = m_glob >> 3, b_ = m_glob & 7;
  const int tau = dir ? (95 - t_) : t_;
  const float* arow = xb + ((size_t)(b_ * 96 + tau)) * 256;

  const int bk = tid >> 4, bn = (tid & 15) * 4;

  for (int kb = 0; kb < 256; kb += 16) {
    float4 av = *(const float4*)(arow + kb + ak);
    As[ak + 0][am] = av.x; As[ak + 1][am] = av.y; As[ak + 2][am] = av.z; As[ak + 3][am] = av.w;

    size_t bidx = ((size_t)dl * 256 + (kb + bk)) * 8192 + (size_t)nt * 64 + bn;
    float b0, b1, b2, b3;
    if (BF) {
      ushort4 uv = *(const ushort4*)((const unsigned short*)Wk + bidx);
      b0 = __uint_as_float(((unsigned)uv.x) << 16);
      b1 = __uint_as_float(((unsigned)uv.y) << 16);
      b2 = __uint_as_float(((unsigned)uv.z) << 16);
      b3 = __uint_as_float(((unsigned)uv.w) << 16);
    } else {
      float4 fv = *(const float4*)((const float*)Wk + bidx);
      b0 = fv.x; b1 = fv.y; b2 = fv.z; b3 = fv.w;
    }
    Bs[bk][bn + 0] = b0; Bs[bk][bn + 1] = b1; Bs[bk][bn + 2] = b2; Bs[bk][bn + 3] = b3;
    __syncthreads();

#pragma unroll
    for (int kk = 0; kk < 16; ++kk) {
      float a0 = As[kk][ty * 4 + 0], a1 = As[kk][ty * 4 + 1], a2 = As[kk][ty * 4 + 2], a3 = As[kk][ty * 4 + 3];
      float c0 = Bs[kk][tx * 4 + 0], c1 = Bs[kk][tx * 4 + 1], c2 = Bs[kk][tx * 4 + 2], c3 = Bs[kk][tx * 4 + 3];
      acc[0][0] = fmaf(a0, c0, acc[0][0]); acc[0][1] = fmaf(a0, c1, acc[0][1]);
      acc[0][2] = fmaf(a0, c2, acc[0][2]); acc[0][3] = fmaf(a0, c3, acc[0][3]);
      acc[1][0] = fmaf(a1, c0, acc[1][0]); acc[1][1] = fmaf(a1, c1, acc[1][1]);
      acc[1][2] = fmaf(a1, c2, acc[1][2]); acc[1][3] = fmaf(a1, c3, acc[1][3]);
      acc[2][0] = fmaf(a2, c0, acc[2][0]); acc[2][1] = fmaf(a2, c1, acc[2][1]);
      acc[2][2] = fmaf(a2, c2, acc[2][2]); acc[2][3] = fmaf(a2, c3, acc[2][3]);
      acc[3][0] = fmaf(a3, c0, acc[3][0]); acc[3][1] = fmaf(a3, c1, acc[3][1]);
      acc[3][2] = fmaf(a3, c2, acc[3][2]); acc[3][3] = fmaf(a3, c3, acc[3][3]);
    }
    __syncthreads();
  }

  const int n0 = nt * 64 + tx * 4;
#pragma unroll
  for (int i = 0; i < 4; ++i) {
    int m = mt * 64 + ty * 4 + i;
    int tt = m >> 3, bb = m & 7;
    float4 o;
    o.x = acc[i][0] + bias32[dl * 8192 + n0 + 0];
    o.y = acc[i][1] + bias32[dl * 8192 + n0 + 1];
    o.z = acc[i][2] + bias32[dl * 8192 + n0 + 2];
    o.w = acc[i][3] + bias32[dl * 8192 + n0 + 3];
    *(float4*)(xW + (size_t)((dir * 96 + tt) * 8 + bb) * 8192 + n0) = o;
  }
}

// ---------------- barrier protocol ----------------
// Arrival (proven, round-2): fetch_add on 64 padded lines (4 wgs/line).
// Barrier B poll (proven): ONE atomic load per lane (64 lanes x 64 lines) + __all.
// Barrier A poll (NEW, round-6): ELIMINATED -- phase 2 gates each 4-line chunk
// of its y-consumption on the producers' line counters, pipelined one chunk
// ahead so polling overlaps FMAs. Safety: first-false-pass induction -- a line
// can only reach 4*(2t+1) after all 4 of its wgs A-arrived (no B-bump of step
// t can precede global A-completion). Chunk order rotated per (wg,wave) to
// spread initial poll traffic over all 64 lines (round-4 law: hot lines cost).
// Data protocol (validated): relaxed AGENT data stores to MALL, wave-level
// vmcnt drain before arrival, plain cached loads of per-step-unique data
// addresses, compiler fence after each gate, NO acquire anywhere.

// ---------------- persistent LSTM scan ----------------
__global__ __launch_bounds__(256, 2) void scan_kernel(
    const float* __restrict__ xW, const void* __restrict__ WrRaw, const void* __restrict__ maskp,
    const float* __restrict__ WpT, const float* __restrict__ mask32,
    float* __restrict__ out, float* __restrict__ hbuf, float* __restrict__ ybuf,
    int* ctrs, int layer) {
  const int tid = threadIdx.x;
  const int w = blockIdx.x;
  const int dir = w >> 8;
  const int g = w & 255;
  const int dl = dir * 2 + layer;

  __shared__ __align__(16) float wr_s[256 * 32];   // 32 KB
  __shared__ __align__(16) float h_lds[2048];      // 8 KB
  __shared__ float4 wp4_s[512];                    // 8 KB
  __shared__ float4 zpart[288];                    // 4.5 KB (stride-9 pad)
  __shared__ float  z_s[32 * 9];                   // 1.1 KB (stride-9 pad)
  __shared__ __align__(16) float xw_s[256];        // 1 KB
  __shared__ float  mask_s[768];                   // 3 KB
  __shared__ float  c_s[64];
  __shared__ float  red_s[8];

  int* base   = ctrs + (layer * 2 + dir) * 4096;   // 64 lines x 64 ints
  int* aline  = base + (g >> 2) * 64;              // my arrival line (4 wgs each)
  int* myline = base + (tid & 63) * 64;            // poll line for wave-0 lanes (barrier B)
  int ep = 0;
  const int bf = detect_bf(maskp);

  // one-time loads
  {
    const size_t wrbase = (size_t)dl * 256 * 8192;
    for (int i = tid; i < 8192; i += 256) {
      int k = i >> 5, col = i & 31;
      wr_s[i] = ldraw(WrRaw, wrbase + (size_t)k * 8192 + (size_t)(col >> 3) * 2048 + g * 8 + (col & 7), bf);
    }
    const float4* wrow = (const float4*)(WpT + ((size_t)(dl * 256 + g)) * 2048);
    for (int i = tid; i < 512; i += 256) wp4_s[i] = wrow[i];
    for (int i = tid; i < 768; i += 256) mask_s[i] = mask32[i];
  }
  if (tid < 64) c_s[tid] = 0.f;

  // prologue: xW[t=0] into xw_s (visible after first loop-top __syncthreads)
  {
    const int bb = tid >> 5, cc = tid & 31;
    xw_s[tid] = xW[(size_t)((dir * 96 + 0) * 8 + bb) * 8192 + (cc >> 3) * 2048 + g * 8 + (cc & 7)];
  }

  const int ks = tid >> 6, colq = (tid >> 3) & 7, lb = tid & 7;
  const float4* wr4 = (const float4*)wr_s;
  const float4* xw4 = (const float4*)xw_s;

  for (int t = 0; t < 96; ++t) {
    const int tau = dir ? (95 - t) : t;
    const float* h_cur = hbuf + ((size_t)(t * 2 + dir)) * 2048;
    float* h_nxt = hbuf + ((size_t)((t + 1) * 2 + dir)) * 2048;
    float* y_t   = ybuf + ((size_t)(t * 2 + dir)) * 16384;

    // h copy into LDS, layout [p*8+b]
    if (t == 0) {
      ((float4*)h_lds)[tid * 2 + 0] = make_float4(0.f, 0.f, 0.f, 0.f);
      ((float4*)h_lds)[tid * 2 + 1] = make_float4(0.f, 0.f, 0.f, 0.f);
    } else {
      ((float4*)h_lds)[tid * 2 + 0] = ((const float4*)h_cur)[tid * 2 + 0];
      ((float4*)h_lds)[tid * 2 + 1] = ((const float4*)h_cur)[tid * 2 + 1];
    }
    __syncthreads();

    // ---- phase 1: z = xW[t] + h @ Wr ----
    {
      float4 acc = make_float4(0.f, 0.f, 0.f, 0.f);
#pragma unroll 16
      for (int i = 0; i < 64; ++i) {
        int k = (ks << 6) + i;
        float hv = h_lds[k * 8 + lb];
        float4 wv = wr4[k * 8 + colq];
        acc.x = fmaf(hv, wv.x, acc.x); acc.y = fmaf(hv, wv.y, acc.y);
        acc.z = fmaf(hv, wv.z, acc.z); acc.w = fmaf(hv, wv.w, acc.w);
      }
      zpart[(ks * 8 + colq) * 9 + lb] = acc;
    }
    __syncthreads();

    ++ep;  // A epoch (target 4*ep per line once all 4 wgs arrived)
    if (tid < 64) {
      {
        const int b3 = tid & 7, cq = tid >> 3;
        float4 z0 = zpart[(0 * 8 + cq) * 9 + b3];
        float4 z1 = zpart[(1 * 8 + cq) * 9 + b3];
        float4 z2 = zpart[(2 * 8 + cq) * 9 + b3];
        float4 z3 = zpart[(3 * 8 + cq) * 9 + b3];
        float4 xv = xw4[b3 * 8 + cq];
        z_s[(cq * 4 + 0) * 9 + b3] = z0.x + z1.x + z2.x + z3.x + xv.x;
        z_s[(cq * 4 + 1) * 9 + b3] = z0.y + z1.y + z2.y + z3.y + xv.y;
        z_s[(cq * 4 + 2) * 9 + b3] = z0.z + z1.z + z2.z + z3.z + xv.z;
        z_s[(cq * 4 + 3) * 9 + b3] = z0.w + z1.w + z2.w + z3.w + xv.w;
        const int cell = cq;
        float zi = z_s[(0  + cell) * 9 + b3];
        float zf = z_s[(8  + cell) * 9 + b3];
        float zg = z_s[(16 + cell) * 9 + b3];
        float zo = z_s[(24 + cell) * 9 + b3];
        float ig = sigm(zi), fg = sigm(zf), gg = tanhf(zg), og = sigm(zo);
        float cold = c_s[tid];
        float cc = clip3(fg * cold + ig * gg);
        float yv = og * tanhf(cc);
        float m = mask_s[b3 * 96 + tau];
        c_s[tid] = (m > 0.f) ? cc : cold;
        __hip_atomic_store(&y_t[b3 * 2048 + g * 8 + cell], yv, __ATOMIC_RELAXED, __HIP_MEMORY_SCOPE_AGENT);
      }
      // drain y store and arrive; NO poll here (phase 2 gates per line)
      asm volatile("s_waitcnt vmcnt(0)" ::: "memory");
      if (tid == 0)
        __hip_atomic_fetch_add(aline, 1, __ATOMIC_RELAXED, __HIP_MEMORY_SCOPE_AGENT);
    }
    __syncthreads();

    // ---- phase 2: h[p=g] = clip(y @ Wp), per-chunk producer-line gating ----
    {
      const int b = tid >> 5, kq = tid & 31;
      const int lane = tid & 63;
      const int roto = (g + ((tid >> 6) << 2)) & 15;  // rotate chunk order per wg/wave
      const int tgtA = 4 * ep;
      // prefetch next xW into xw_s via threads 64..191 (off wave-0's drain chain)
      if (t < 95 && tid >= 64 && tid < 192) {
        const int j = (tid - 64) * 2;
        const int bb = j >> 5, cc = j & 31;
        float2 x2 = *(const float2*)(xW + (size_t)((dir * 96 + t + 1) * 8 + bb) * 8192 + (cc >> 3) * 2048 + g * 8 + (cc & 7));
        xw_s[j] = x2.x; xw_s[j + 1] = x2.y;
      }
      const float4* yb = (const float4*)y_t + b * 512;
      float s = 0.f;
      int v = 0x7fffffff;
      if (lane < 4)
        v = __hip_atomic_load(base + ((roto & 15) * 4 + lane) * 64, __ATOMIC_RELAXED, __HIP_MEMORY_SCOPE_AGENT);
      for (int i = 0; i < 16; ++i) {
        const int ic = (i + roto) & 15;
        while (!__all(v >= tgtA)) {
          __builtin_amdgcn_s_sleep(1);
          if (lane < 4)
            v = __hip_atomic_load(base + (ic * 4 + lane) * 64, __ATOMIC_RELAXED, __HIP_MEMORY_SCOPE_AGENT);
        }
        asm volatile("" ::: "memory");   // fence: no y-load hoisting above the gate
        const int k4 = ic * 32 + kq;
        float4 yv = yb[k4];
        float4 wv = wp4_s[k4];
        if (i < 15) {
          const int icn = (i + 1 + roto) & 15;
          if (lane < 4)
            v = __hip_atomic_load(base + (icn * 4 + lane) * 64, __ATOMIC_RELAXED, __HIP_MEMORY_SCOPE_AGENT);
          else v = 0x7fffffff;
        }
        s = fmaf(yv.x, wv.x, s); s = fmaf(yv.y, wv.y, s);
        s = fmaf(yv.z, wv.z, s); s = fmaf(yv.w, wv.w, s);
      }
      s += __shfl_down(s, 16, 32);
      s += __shfl_down(s, 8, 32);
      s += __shfl_down(s, 4, 32);
      s += __shfl_down(s, 2, 32);
      s += __shfl_down(s, 1, 32);
      if (kq == 0) red_s[b] = s;
    }
    __syncthreads();

    ++ep;  // barrier B epoch (full rendezvous, proven form)
    if (tid < 64) {
      float hv = 0.f;
      if (tid < 8) {
        float hc = clip3(red_s[tid]);
        float m = mask_s[tid * 96 + tau];
        float hp = h_lds[g * 8 + tid];         // h_t from LDS (no global re-read)
        hv = (m > 0.f) ? hc : hp;
        __hip_atomic_store(&h_nxt[g * 8 + tid], hv, __ATOMIC_RELAXED, __HIP_MEMORY_SCOPE_AGENT);
      }
      asm volatile("s_waitcnt vmcnt(0)" ::: "memory");   // drains h store only (wave 0 has no prefetch)
      if (tid == 0)
        __hip_atomic_fetch_add(aline, 1, __ATOMIC_RELAXED, __HIP_MEMORY_SCOPE_AGENT);
      const int tgt = 4 * ep;
      int v = __hip_atomic_load(myline, __ATOMIC_RELAXED, __HIP_MEMORY_SCOPE_AGENT);
      while (!__all(v >= tgt)) {
        __builtin_amdgcn_s_sleep(1);
        v = __hip_atomic_load(myline, __ATOMIC_RELAXED, __HIP_MEMORY_SCOPE_AGENT);
      }
      // out store AFTER the poll: keeps the HBM store ack out of the chain
      if (tid < 8)
        out[(size_t)((dir * 8 + tid) * 96 + tau) * 256 + g] = hv;
    }
    __syncthreads();
  }
}

// ---------------- ELMo mix ----------------
DEVFN float layer_val(int l, int b, int t, int f, const float* emb, const float* out0, const float* out1) {
  const int half = f >> 8, p = f & 255;
  if (l == 0) return emb[(size_t)(b * 96 + t) * 256 + p];
  const size_t o = ((size_t)((half * 8 + b) * 96 + t)) * 256 + p;
  float v = out0[o];
  if (l == 2) v += out1[o];
  return v;
}

__global__ void mixA_k(const float* emb, const float* out0, const float* out1,
                       const float* mask32, float* stats) {
  const int b = blockIdx.x / 3, l = blockIdx.x % 3;
  float s1 = 0.f, s2 = 0.f;
  for (int idx = threadIdx.x; idx < 96 * 512; idx += 256) {
    int t = idx >> 9, f = idx & 511;
    float v = layer_val(l, b, t, f, emb, out0, out1);
    float m = mask32[b * 96 + t];
    s1 += m * v; s2 += m * v * v;
  }
  for (int off = 32; off; off >>= 1) { s1 += __shfl_down(s1, off); s2 += __shfl_down(s2, off); }
  __shared__ float p1[4], p2[4];
  if ((threadIdx.x & 63) == 0) { p1[threadIdx.x >> 6] = s1; p2[threadIdx.x >> 6] = s2; }
  __syncthreads();
  if (threadIdx.x == 0) {
    float S1 = p1[0] + p1[1] + p1[2] + p1[3];
    float S2 = p2[0] + p2[1] + p2[2] + p2[3];
    float num = 0.f;
    for (int t = 0; t < 96; ++t) num += mask32[b * 96 + t];
    float mean = S1 / num;
    float var = S2 / num - 2.f * mean * mean + 512.f * mean * mean;
    stats[(b * 3 + l) * 2 + 0] = mean;
    stats[(b * 3 + l) * 2 + 1] = rsqrtf(var + 1e-12f);
  }
}

__global__ void mixB_k(const void* maskp, const float* emb, const float* out0, const float* out1,
                       const float* stats, const float* ew32, void* outp) {
  const int idx = blockIdx.x * 256 + threadIdx.x;
  const int b = idx / 49152;
  const int r = idx % 49152;
  const int t = r >> 9, f = r & 511;
  float w0 = ew32[0], w1 = ew32[1], w2 = ew32[2], gm = ew32[3];
  float mx = fmaxf(w0, fmaxf(w1, w2));
  float e0 = __expf(w0 - mx), e1 = __expf(w1 - mx), e2 = __expf(w2 - mx);
  float inv = 1.f / (e0 + e1 + e2);
  float wl[3] = {e0 * inv, e1 * inv, e2 * inv};
  float acc = 0.f;
#pragma unroll
  for (int l = 0; l < 3; ++l) {
    float v = layer_val(l, b, t, f, emb, out0, out1);
    acc += wl[l] * (v - stats[(b * 3 + l) * 2]) * stats[(b * 3 + l) * 2 + 1];
  }
  acc *= gm;
  if (detect_bf(maskp)) ((__hip_bfloat16*)outp)[idx] = __float2bfloat16(acc);
  else                  ((float*)outp)[idx] = acc;
}

// ---------------- host ----------------
extern "C" void kernel_launch(void* const* d_in, const int* in_sizes, int n_in,
                              void* d_out, int out_size, void* d_ws, size_t ws_size,
                              hipStream_t stream) {
  const int*  tokens = (const int*)d_in[0];
  const void* maskp  = d_in[1];
  const void* embt   = d_in[2];
  const void* Wk     = d_in[3];
  const void* WrRaw  = d_in[4];
  const void* bias   = d_in[5];
  const void* Wp     = d_in[6];
  const void* ew     = d_in[7];
  const void* gm     = d_in[8];

  char* ws = (char*)d_ws;
  int*   ctrs   = (int*)(ws + OFF_CTRS);
  float* stats  = (float*)(ws + OFF_STATS);
  float* ew32   = (float*)(ws + OFF_EW);
  float* mask32 = (float*)(ws + OFF_MASK32);
  float* emb    = (float*)(ws + OFF_EMB);
  float* wpt    = (float*)(ws + OFF_WPT);
  float* bias32 = (float*)(ws + OFF_BIAS);
  float* xW     = (float*)(ws + OFF_XW);
  float* out0   = (float*)(ws + OFF_OUT0);
  float* out1   = (float*)(ws + OFF_OUT1);
  float* ybuf   = (float*)(ws + OFF_Y);
  float* hbuf   = (float*)(ws + OFF_H);

  hipMemsetAsync(d_ws, 0, 131072, stream);

  prep_k<0><<<1412, 256, 0, stream>>>(tokens, maskp, embt, bias, ew, gm, Wp,
                                      bias32, mask32, ew32, emb, wpt);
  prep_k<1><<<1412, 256, 0, stream>>>(tokens, maskp, embt, bias, ew, gm, Wp,
                                      bias32, mask32, ew32, emb, wpt);

  xw_gemm_k<0><<<dim3(128, 12, 2), 256, 0, stream>>>(maskp, emb, emb, Wk, bias32, xW, 0);
  xw_gemm_k<1><<<dim3(128, 12, 2), 256, 0, stream>>>(maskp, emb, emb, Wk, bias32, xW, 0);

  int l0 = 0, l1 = 1;
  {
    void* args[] = {&xW, &WrRaw, &maskp, &wpt, &mask32, &out0, &hbuf, &ybuf, &ctrs, &l0};
    hipError_t e = hipLaunchCooperativeKernel((void*)scan_kernel, dim3(512), dim3(256), args, 0, stream);
    if (e != hipSuccess)
      scan_kernel<<<512, 256, 0, stream>>>(xW, WrRaw, maskp, wpt, mask32, out0, hbuf, ybuf, ctrs, 0);
  }

  float* x_fwd = out0;
  float* x_bwd = out0 + (size_t)8 * 96 * 256;
  xw_gemm_k<0><<<dim3(128, 12, 2), 256, 0, stream>>>(maskp, x_fwd, x_bwd, Wk, bias32, xW, 1);
  xw_gemm_k<1><<<dim3(128, 12, 2), 256, 0, stream>>>(maskp, x_fwd, x_bwd, Wk, bias32, xW, 1);

  {
    void* args[] = {&xW, &WrRaw, &maskp, &wpt, &mask32, &out1, &hbuf, &ybuf, &ctrs, &l1};
    hipError_t e = hipLaunchCooperativeKernel((void*)scan_kernel, dim3(512), dim3(256), args, 0, stream);
    if (e != hipSuccess)
      scan_kernel<<<512, 256, 0, stream>>>(xW, WrRaw, maskp, wpt, mask32, out1, hbuf, ybuf, ctrs, 1);
  }

  mixA_k<<<24, 256, 0, stream>>>(emb, out0, out1, mask32, stats);
  mixB_k<<<1536, 256, 0, stream>>>(maskp, emb, out0, out1, stats, ew32, d_out);
}

// Round 7
// 2298.130 us; speedup vs baseline: 1.2692x; 1.2692x over previous
//
#include <hip/hip_runtime.h>
#include <hip/hip_bf16.h>

#define DEVFN __device__ __forceinline__

// ---- workspace layout (bytes) ----
static constexpr size_t OFF_CTRS   = 0;                          // barrier arenas (zeroed): 4 arenas x 4096 ints = 64KB
static constexpr size_t OFF_STATS  = 131328;                     // 48 floats
static constexpr size_t OFF_EW     = 131584;                     // 4 floats
static constexpr size_t OFF_MASK32 = 131840;                     // 768 floats
static constexpr size_t OFF_EMB    = 135168;                     // 786,432 B
static constexpr size_t OFF_WPT    = 921600;                     // 8,388,608 B
static constexpr size_t OFF_BIAS   = 9310208;                    // 131,072 B
static constexpr size_t OFF_XW     = 9441280;                    // 50,331,648 B
static constexpr size_t OFF_OUT0   = 59772928;                   // 1,572,864 B
static constexpr size_t OFF_OUT1   = 61345792;                   // 1,572,864 B
static constexpr size_t OFF_Y      = 62918656;                   // 96*2*16384*4
static constexpr size_t OFF_H      = 75501568;                   // 97*2*2048*4

template<int BF>
DEVFN float ldin(const void* p, size_t i) {
  if (BF) {
    unsigned short u = ((const unsigned short*)p)[i];
    return __uint_as_float(((unsigned)u) << 16);
  }
  return ((const float*)p)[i];
}
DEVFN float ldraw(const void* p, size_t i, int bf) {
  if (bf) {
    unsigned short u = ((const unsigned short*)p)[i];
    return __uint_as_float(((unsigned)u) << 16);
  }
  return ((const float*)p)[i];
}

DEVFN float sigm(float x) { return 1.f / (1.f + __expf(-x)); }
DEVFN float clip3(float x) { return fminf(fmaxf(x, -3.f), 3.f); }

// dtype self-detection
DEVFN int detect_bf(const void* maskp) {
  return (((const unsigned*)maskp)[0] == 0x3F800000u) ? 0 : 1;
}

// ---------------- fused prep: convert + Wp transpose + embedding gather ----------------
template<int BF>
__global__ void prep_k(const int* __restrict__ tokens, const void* __restrict__ maskp,
                       const void* __restrict__ et, const void* __restrict__ bias,
                       const void* __restrict__ ew, const void* __restrict__ gm,
                       const void* __restrict__ Wp,
                       float* bias32, float* mask32, float* ew32, float* emb, float* WpT) {
  if (detect_bf(maskp) != BF) return;
  const int bid = blockIdx.x, tid = threadIdx.x;

  if (bid < 132) {
    size_t i = (size_t)bid * 256 + tid;
    if (i >= 33540) return;
    if (i < 32768)       bias32[i] = ldin<BF>(bias, i);
    else if (i < 33536)  mask32[i - 32768] = ldin<BF>(maskp, i - 32768);
    else if (i < 33539)  ew32[i - 33536]   = ldin<BF>(ew, i - 33536);
    else                 ew32[3] = ldin<BF>(gm, 0);
    return;
  }

  if (bid < 644) {
    const int r = bid - 132;
    const int kt = r & 31, pt = (r >> 5) & 3, dl = r >> 7;
    __shared__ float tile[64][65];
    for (int it = 0; it < 4; ++it) {
      int lin = it * 1024 + tid * 4;
      int kk = lin >> 6, pp = lin & 63;
      size_t src = ((size_t)(dl * 2048 + kt * 64 + kk)) * 256 + pt * 64 + pp;
      float v0, v1, v2, v3;
      if (BF) {
        const unsigned short* sp = (const unsigned short*)Wp + src;
        v0 = __uint_as_float(((unsigned)sp[0]) << 16);
        v1 = __uint_as_float(((unsigned)sp[1]) << 16);
        v2 = __uint_as_float(((unsigned)sp[2]) << 16);
        v3 = __uint_as_float(((unsigned)sp[3]) << 16);
      } else {
        float4 v = *(const float4*)((const float*)Wp + src);
        v0 = v.x; v1 = v.y; v2 = v.z; v3 = v.w;
      }
      tile[pp + 0][kk] = v0; tile[pp + 1][kk] = v1; tile[pp + 2][kk] = v2; tile[pp + 3][kk] = v3;
    }
    __syncthreads();
    for (int it = 0; it < 4; ++it) {
      int lin = it * 1024 + tid * 4;
      int pr = lin >> 6, kc = lin & 63;
      float4 o;
      o.x = tile[pr][kc + 0]; o.y = tile[pr][kc + 1]; o.z = tile[pr][kc + 2]; o.w = tile[pr][kc + 3];
      *(float4*)(WpT + ((size_t)(dl * 256 + pt * 64 + pr)) * 2048 + kt * 64 + kc) = o;
    }
    return;
  }

  const int bt = bid - 644;
  const int tok = tokens[bt];
  emb[(size_t)bt * 256 + tid] = ldin<BF>(et, (size_t)tok * 256 + tid);
}

// ---------------- xW = x @ Wk[dl] + b[dl] ----------------
template<int BF>
__global__ __launch_bounds__(256) void xw_gemm_k(
    const void* __restrict__ maskp, const float* __restrict__ x_fwd, const float* __restrict__ x_bwd,
    const void* __restrict__ Wk, const float* __restrict__ bias32, float* __restrict__ xW, int layer) {
  if (detect_bf(maskp) != BF) return;
  const int nt = blockIdx.x, mt = blockIdx.y, dir = blockIdx.z;
  const int dl = dir * 2 + layer;
  const float* xb = dir ? x_bwd : x_fwd;
  const int tid = threadIdx.x;

  __shared__ float As[16][68];
  __shared__ float Bs[16][68];

  float acc[4][4] = {};
  const int tx = tid & 15, ty = tid >> 4;

  const int am = tid >> 2;
  const int ak = (tid & 3) * 4;
  const int m_glob = mt * 64 + am;
  const int t_ = m_glob >> 3, b_ = m_glob & 7;
  const int tau = dir ? (95 - t_) : t_;
  const float* arow = xb + ((size_t)(b_ * 96 + tau)) * 256;

  const int bk = tid >> 4, bn = (tid & 15) * 4;

  for (int kb = 0; kb < 256; kb += 16) {
    float4 av = *(const float4*)(arow + kb + ak);
    As[ak + 0][am] = av.x; As[ak + 1][am] = av.y; As[ak + 2][am] = av.z; As[ak + 3][am] = av.w;

    size_t bidx = ((size_t)dl * 256 + (kb + bk)) * 8192 + (size_t)nt * 64 + bn;
    float b0, b1, b2, b3;
    if (BF) {
      ushort4 uv = *(const ushort4*)((const unsigned short*)Wk + bidx);
      b0 = __uint_as_float(((unsigned)uv.x) << 16);
      b1 = __uint_as_float(((unsigned)uv.y) << 16);
      b2 = __uint_as_float(((unsigned)uv.z) << 16);
      b3 = __uint_as_float(((unsigned)uv.w) << 16);
    } else {
      float4 fv = *(const float4*)((const float*)Wk + bidx);
      b0 = fv.x; b1 = fv.y; b2 = fv.z; b3 = fv.w;
    }
    Bs[bk][bn + 0] = b0; Bs[bk][bn + 1] = b1; Bs[bk][bn + 2] = b2; Bs[bk][bn + 3] = b3;
    __syncthreads();

#pragma unroll
    for (int kk = 0; kk < 16; ++kk) {
      float a0 = As[kk][ty * 4 + 0], a1 = As[kk][ty * 4 + 1], a2 = As[kk][ty * 4 + 2], a3 = As[kk][ty * 4 + 3];
      float c0 = Bs[kk][tx * 4 + 0], c1 = Bs[kk][tx * 4 + 1], c2 = Bs[kk][tx * 4 + 2], c3 = Bs[kk][tx * 4 + 3];
      acc[0][0] = fmaf(a0, c0, acc[0][0]); acc[0][1] = fmaf(a0, c1, acc[0][1]);
      acc[0][2] = fmaf(a0, c2, acc[0][2]); acc[0][3] = fmaf(a0, c3, acc[0][3]);
      acc[1][0] = fmaf(a1, c0, acc[1][0]); acc[1][1] = fmaf(a1, c1, acc[1][1]);
      acc[1][2] = fmaf(a1, c2, acc[1][2]); acc[1][3] = fmaf(a1, c3, acc[1][3]);
      acc[2][0] = fmaf(a2, c0, acc[2][0]); acc[2][1] = fmaf(a2, c1, acc[2][1]);
      acc[2][2] = fmaf(a2, c2, acc[2][2]); acc[2][3] = fmaf(a2, c3, acc[2][3]);
      acc[3][0] = fmaf(a3, c0, acc[3][0]); acc[3][1] = fmaf(a3, c1, acc[3][1]);
      acc[3][2] = fmaf(a3, c2, acc[3][2]); acc[3][3] = fmaf(a3, c3, acc[3][3]);
    }
    __syncthreads();
  }

  const int n0 = nt * 64 + tx * 4;
#pragma unroll
  for (int i = 0; i < 4; ++i) {
    int m = mt * 64 + ty * 4 + i;
    int tt = m >> 3, bb = m & 7;
    float4 o;
    o.x = acc[i][0] + bias32[dl * 8192 + n0 + 0];
    o.y = acc[i][1] + bias32[dl * 8192 + n0 + 1];
    o.z = acc[i][2] + bias32[dl * 8192 + n0 + 2];
    o.w = acc[i][3] + bias32[dl * 8192 + n0 + 3];
    *(float4*)(xW + (size_t)((dir * 96 + tt) * 8 + bb) * 8192 + n0) = o;
  }
}

// ---------------- sync (round-2 proven form, UNCHANGED) ----------------
// MEASURED LAWS: (r2/r5=1000us, r4=1150, r6=1275) arrival = fetch_add on 64
// padded lines (4 wgs/line); poll = ONE atomic load per lane (64 lanes x 64
// lines) + __all. Any wider poll regresses. Global rendezvous floor ~2us.
// ROUND-7 CHANGE: don't fight the floor -- HIDE it. One wg owns BOTH dirs of
// its g-column (fwd+bwd Wr slices in LDS, 107KB, 1 wg/CU, 256 wgs). Schedule
// interleaves the two independent recurrences so each barrier's propagation
// overlaps the other dir's compute. Protocol, arithmetic, per-arena traffic
// all identical to round 5 -- only schedule + residency changed.
DEVFN void arrive(int* aline, int tid) {
  asm volatile("s_waitcnt vmcnt(0)" ::: "memory");
  if (tid == 0)
    __hip_atomic_fetch_add(aline, 1, __ATOMIC_RELAXED, __HIP_MEMORY_SCOPE_AGENT);
}
DEVFN void poll64(int* myline, int tgt) {
  int v = __hip_atomic_load(myline, __ATOMIC_RELAXED, __HIP_MEMORY_SCOPE_AGENT);
  while (!__all(v >= tgt)) {
    __builtin_amdgcn_s_sleep(1);
    v = __hip_atomic_load(myline, __ATOMIC_RELAXED, __HIP_MEMORY_SCOPE_AGENT);
  }
}

// ---------------- persistent LSTM scan: dir-interleaved ----------------
__global__ __launch_bounds__(256, 1) void scan_kernel(
    const float* __restrict__ xW, const void* __restrict__ WrRaw, const void* __restrict__ maskp,
    const float* __restrict__ WpT, const float* __restrict__ mask32,
    float* __restrict__ out, float* __restrict__ hbuf, float* __restrict__ ybuf,
    int* ctrs, int layer) {
  const int tid = threadIdx.x;
  const int g = blockIdx.x;            // 0..255
  const int dlf = layer, dlb = 2 + layer;

  __shared__ __align__(16) float wr_f[256 * 32];   // 32 KB
  __shared__ __align__(16) float wr_b[256 * 32];   // 32 KB
  __shared__ __align__(16) float hf_lds[2048];     // 8 KB
  __shared__ __align__(16) float hb_lds[2048];     // 8 KB
  __shared__ float4 wpf_s[512];                    // 8 KB
  __shared__ float4 wpb_s[512];                    // 8 KB
  __shared__ float4 zpart[288];                    // 4.5 KB (shared: dirs use it sequentially)
  __shared__ float  z_s[32 * 9];                   // 1.1 KB
  __shared__ __align__(16) float xwf_s[256];       // 1 KB
  __shared__ __align__(16) float xwb_s[256];       // 1 KB
  __shared__ float  mask_s[768];                   // 3 KB
  __shared__ float  cf_s[64], cb_s[64];
  __shared__ float  red_s[8];
  // total ~107 KB -> 1 wg/CU (gfx950 allows >64KB static LDS; cf. 8-phase example 128KB)

  int* arena_f = ctrs + (layer * 2 + 0) * 4096;
  int* arena_b = ctrs + (layer * 2 + 1) * 4096;
  int* alf = arena_f + (g >> 2) * 64;
  int* alb = arena_b + (g >> 2) * 64;
  int* mlf = arena_f + (tid & 63) * 64;
  int* mlb = arena_b + (tid & 63) * 64;
  int epf = 0, epb = 0;
  const int bf = detect_bf(maskp);

  // one-time loads (both dirs)
  {
    const size_t wbf = (size_t)dlf * 256 * 8192;
    const size_t wbb = (size_t)dlb * 256 * 8192;
    for (int i = tid; i < 8192; i += 256) {
      int k = i >> 5, col = i & 31;
      size_t off = (size_t)k * 8192 + (size_t)(col >> 3) * 2048 + g * 8 + (col & 7);
      wr_f[i] = ldraw(WrRaw, wbf + off, bf);
      wr_b[i] = ldraw(WrRaw, wbb + off, bf);
    }
    const float4* wrf = (const float4*)(WpT + ((size_t)(dlf * 256 + g)) * 2048);
    const float4* wrb = (const float4*)(WpT + ((size_t)(dlb * 256 + g)) * 2048);
    for (int i = tid; i < 512; i += 256) { wpf_s[i] = wrf[i]; wpb_s[i] = wrb[i]; }
    for (int i = tid; i < 768; i += 256) mask_s[i] = mask32[i];
  }
  if (tid < 64) { cf_s[tid] = 0.f; cb_s[tid] = 0.f; }
  {
    const int bb2 = tid >> 5, cc = tid & 31;
    xwf_s[tid] = xW[(size_t)((0 * 96 + 0) * 8 + bb2) * 8192 + (cc >> 3) * 2048 + g * 8 + (cc & 7)];
    xwb_s[tid] = xW[(size_t)((1 * 96 + 0) * 8 + bb2) * 8192 + (cc >> 3) * 2048 + g * 8 + (cc & 7)];
  }
  {
    float4 z4 = make_float4(0.f, 0.f, 0.f, 0.f);
    ((float4*)hf_lds)[tid * 2 + 0] = z4; ((float4*)hf_lds)[tid * 2 + 1] = z4;
    ((float4*)hb_lds)[tid * 2 + 0] = z4; ((float4*)hb_lds)[tid * 2 + 1] = z4;
  }
  __syncthreads();

  const int ks = tid >> 6, colq = (tid >> 3) & 7, lb = tid & 7;
  const float4* wr4f = (const float4*)wr_f;
  const float4* wr4b = (const float4*)wr_b;
  const float4* xw4f = (const float4*)xwf_s;
  const float4* xw4b = (const float4*)xwb_s;

  for (int t = 0; t < 96; ++t) {
    const int tauf = t, taub = 95 - t;
    float* yf  = ybuf + ((size_t)(t * 2 + 0)) * 16384;
    float* yb_ = ybuf + ((size_t)(t * 2 + 1)) * 16384;
    float* hnf = hbuf + ((size_t)((t + 1) * 2 + 0)) * 2048;
    float* hnb = hbuf + ((size_t)((t + 1) * 2 + 1)) * 2048;

    // ---- P1F: z_f = xW_f + h_f @ Wr_f ----
    {
      float4 acc = make_float4(0.f, 0.f, 0.f, 0.f);
#pragma unroll 16
      for (int i = 0; i < 64; ++i) {
        int k = (ks << 6) + i;
        float hv = hf_lds[k * 8 + lb];
        float4 wv = wr4f[k * 8 + colq];
        acc.x = fmaf(hv, wv.x, acc.x); acc.y = fmaf(hv, wv.y, acc.y);
        acc.z = fmaf(hv, wv.z, acc.z); acc.w = fmaf(hv, wv.w, acc.w);
      }
      zpart[(ks * 8 + colq) * 9 + lb] = acc;
    }
    __syncthreads();

    ++epf;  // A_f
    if (tid < 64) {
      const int b3 = tid & 7, cq = tid >> 3;
      float4 z0 = zpart[(0 * 8 + cq) * 9 + b3];
      float4 z1 = zpart[(1 * 8 + cq) * 9 + b3];
      float4 z2 = zpart[(2 * 8 + cq) * 9 + b3];
      float4 z3 = zpart[(3 * 8 + cq) * 9 + b3];
      float4 xv = xw4f[b3 * 8 + cq];
      z_s[(cq * 4 + 0) * 9 + b3] = z0.x + z1.x + z2.x + z3.x + xv.x;
      z_s[(cq * 4 + 1) * 9 + b3] = z0.y + z1.y + z2.y + z3.y + xv.y;
      z_s[(cq * 4 + 2) * 9 + b3] = z0.z + z1.z + z2.z + z3.z + xv.z;
      z_s[(cq * 4 + 3) * 9 + b3] = z0.w + z1.w + z2.w + z3.w + xv.w;
      const int cell = cq;
      float zi = z_s[(0  + cell) * 9 + b3];
      float zf = z_s[(8  + cell) * 9 + b3];
      float zg = z_s[(16 + cell) * 9 + b3];
      float zo = z_s[(24 + cell) * 9 + b3];
      float ig = sigm(zi), fg = sigm(zf), gg = tanhf(zg), og = sigm(zo);
      float cold = cf_s[tid];
      float cc = clip3(fg * cold + ig * gg);
      float yv = og * tanhf(cc);
      float m = mask_s[b3 * 96 + tauf];
      cf_s[tid] = (m > 0.f) ? cc : cold;
      __hip_atomic_store(&yf[b3 * 2048 + g * 8 + cell], yv, __ATOMIC_RELAXED, __HIP_MEMORY_SCOPE_AGENT);
      arrive(alf, tid);
    }
    __syncthreads();

    // ---- P1B: z_b = xW_b + h_b @ Wr_b (hides A_f propagation) ----
    {
      float4 acc = make_float4(0.f, 0.f, 0.f, 0.f);
#pragma unroll 16
      for (int i = 0; i < 64; ++i) {
        int k = (ks << 6) + i;
        float hv = hb_lds[k * 8 + lb];
        float4 wv = wr4b[k * 8 + colq];
        acc.x = fmaf(hv, wv.x, acc.x); acc.y = fmaf(hv, wv.y, acc.y);
        acc.z = fmaf(hv, wv.z, acc.z); acc.w = fmaf(hv, wv.w, acc.w);
      }
      zpart[(ks * 8 + colq) * 9 + lb] = acc;
    }
    __syncthreads();

    ++epb;  // A_b
    if (tid < 64) {
      const int b3 = tid & 7, cq = tid >> 3;
      float4 z0 = zpart[(0 * 8 + cq) * 9 + b3];
      float4 z1 = zpart[(1 * 8 + cq) * 9 + b3];
      float4 z2 = zpart[(2 * 8 + cq) * 9 + b3];
      float4 z3 = zpart[(3 * 8 + cq) * 9 + b3];
      float4 xv = xw4b[b3 * 8 + cq];
      z_s[(cq * 4 + 0) * 9 + b3] = z0.x + z1.x + z2.x + z3.x + xv.x;
      z_s[(cq * 4 + 1) * 9 + b3] = z0.y + z1.y + z2.y + z3.y + xv.y;
      z_s[(cq * 4 + 2) * 9 + b3] = z0.z + z1.z + z2.z + z3.z + xv.z;
      z_s[(cq * 4 + 3) * 9 + b3] = z0.w + z1.w + z2.w + z3.w + xv.w;
      const int cell = cq;
      float zi = z_s[(0  + cell) * 9 + b3];
      float zf = z_s[(8  + cell) * 9 + b3];
      float zg = z_s[(16 + cell) * 9 + b3];
      float zo = z_s[(24 + cell) * 9 + b3];
      float ig = sigm(zi), fg = sigm(zf), gg = tanhf(zg), og = sigm(zo);
      float cold = cb_s[tid];
      float cc = clip3(fg * cold + ig * gg);
      float yv = og * tanhf(cc);
      float m = mask_s[b3 * 96 + taub];
      cb_s[tid] = (m > 0.f) ? cc : cold;
      __hip_atomic_store(&yb_[b3 * 2048 + g * 8 + cell], yv, __ATOMIC_RELAXED, __HIP_MEMORY_SCOPE_AGENT);
      arrive(alb, tid);
    }
    __syncthreads();

    // ---- wait A_f (mostly elapsed under P1B) ----
    if (tid < 64) poll64(mlf, 4 * epf);
    __syncthreads();

    // ---- P2F: h_f = clip(y_f @ Wp_f) ----
    {
      if (t < 95 && tid >= 64 && tid < 192) {   // xW_f[t+1] prefetch (xwf_s free after P1F)
        const int j = (tid - 64) * 2;
        const int bb2 = j >> 5, cc = j & 31;
        float2 x2 = *(const float2*)(xW + (size_t)((0 * 96 + t + 1) * 8 + bb2) * 8192 + (cc >> 3) * 2048 + g * 8 + (cc & 7));
        xwf_s[j] = x2.x; xwf_s[j + 1] = x2.y;
      }
      const int b = tid >> 5, kq = tid & 31;
      const float4* yb4 = (const float4*)yf + b * 512;
      float s = 0.f;
#pragma unroll 8
      for (int i = 0; i < 16; ++i) {
        int k4 = i * 32 + kq;
        float4 yv = yb4[k4];
        float4 wv = wpf_s[k4];
        s = fmaf(yv.x, wv.x, s); s = fmaf(yv.y, wv.y, s);
        s = fmaf(yv.z, wv.z, s); s = fmaf(yv.w, wv.w, s);
      }
      s += __shfl_down(s, 16, 32);
      s += __shfl_down(s, 8, 32);
      s += __shfl_down(s, 4, 32);
      s += __shfl_down(s, 2, 32);
      s += __shfl_down(s, 1, 32);
      if (kq == 0) red_s[b] = s;
    }
    __syncthreads();

    ++epf;  // B_f
    if (tid < 64) {
      float hv = 0.f;
      if (tid < 8) {
        float hc = clip3(red_s[tid]);
        float m = mask_s[tid * 96 + tauf];
        float hp = hf_lds[g * 8 + tid];
        hv = (m > 0.f) ? hc : hp;
        __hip_atomic_store(&hnf[g * 8 + tid], hv, __ATOMIC_RELAXED, __HIP_MEMORY_SCOPE_AGENT);
      }
      arrive(alf, tid);
      poll64(mlb, 4 * epb);                 // wait A_b (elapsed under P2F)
      if (tid < 8)
        out[(size_t)((0 * 8 + tid) * 96 + tauf) * 256 + g] = hv;
    }
    __syncthreads();

    // ---- P2B: h_b = clip(y_b @ Wp_b) ----
    {
      if (t < 95 && tid >= 64 && tid < 192) {   // xW_b[t+1] prefetch
        const int j = (tid - 64) * 2;
        const int bb2 = j >> 5, cc = j & 31;
        float2 x2 = *(const float2*)(xW + (size_t)((1 * 96 + t + 1) * 8 + bb2) * 8192 + (cc >> 3) * 2048 + g * 8 + (cc & 7));
        xwb_s[j] = x2.x; xwb_s[j + 1] = x2.y;
      }
      const int b = tid >> 5, kq = tid & 31;
      const float4* yb4 = (const float4*)yb_ + b * 512;
      float s = 0.f;
#pragma unroll 8
      for (int i = 0; i < 16; ++i) {
        int k4 = i * 32 + kq;
        float4 yv = yb4[k4];
        float4 wv = wpb_s[k4];
        s = fmaf(yv.x, wv.x, s); s = fmaf(yv.y, wv.y, s);
        s = fmaf(yv.z, wv.z, s); s = fmaf(yv.w, wv.w, s);
      }
      s += __shfl_down(s, 16, 32);
      s += __shfl_down(s, 8, 32);
      s += __shfl_down(s, 4, 32);
      s += __shfl_down(s, 2, 32);
      s += __shfl_down(s, 1, 32);
      if (kq == 0) red_s[b] = s;
    }
    __syncthreads();

    ++epb;  // B_b
    if (tid < 64) {
      float hv = 0.f;
      if (tid < 8) {
        float hc = clip3(red_s[tid]);
        float m = mask_s[tid * 96 + taub];
        float hp = hb_lds[g * 8 + tid];
        hv = (m > 0.f) ? hc : hp;
        __hip_atomic_store(&hnb[g * 8 + tid], hv, __ATOMIC_RELAXED, __HIP_MEMORY_SCOPE_AGENT);
      }
      arrive(alb, tid);
      poll64(mlf, 4 * epf);                 // wait B_f (elapsed under P2B)
      if (tid < 8)
        out[(size_t)((1 * 8 + tid) * 96 + taub) * 256 + g] = hv;
    }
    __syncthreads();

    // h_f reload for t+1 (B_f globally done); overlaps B_b propagation
    ((float4*)hf_lds)[tid * 2 + 0] = ((const float4*)hnf)[tid * 2 + 0];
    ((float4*)hf_lds)[tid * 2 + 1] = ((const float4*)hnf)[tid * 2 + 1];
    if (tid < 64) poll64(mlb, 4 * epb);     // wait B_b
    __syncthreads();
    // h_b reload; ordered before P1B's reads by the sync after P1F's zpart write
    ((float4*)hb_lds)[tid * 2 + 0] = ((const float4*)hnb)[tid * 2 + 0];
    ((float4*)hb_lds)[tid * 2 + 1] = ((const float4*)hnb)[tid * 2 + 1];
  }
}

// ---------------- ELMo mix ----------------
DEVFN float layer_val(int l, int b, int t, int f, const float* emb, const float* out0, const float* out1) {
  const int half = f >> 8, p = f & 255;
  if (l == 0) return emb[(size_t)(b * 96 + t) * 256 + p];
  const size_t o = ((size_t)((half * 8 + b) * 96 + t)) * 256 + p;
  float v = out0[o];
  if (l == 2) v += out1[o];
  return v;
}

__global__ void mixA_k(const float* emb, const float* out0, const float* out1,
                       const float* mask32, float* stats) {
  const int b = blockIdx.x / 3, l = blockIdx.x % 3;
  float s1 = 0.f, s2 = 0.f;
  for (int idx = threadIdx.x; idx < 96 * 512; idx += 256) {
    int t = idx >> 9, f = idx & 511;
    float v = layer_val(l, b, t, f, emb, out0, out1);
    float m = mask32[b * 96 + t];
    s1 += m * v; s2 += m * v * v;
  }
  for (int off = 32; off; off >>= 1) { s1 += __shfl_down(s1, off); s2 += __shfl_down(s2, off); }
  __shared__ float p1[4], p2[4];
  if ((threadIdx.x & 63) == 0) { p1[threadIdx.x >> 6] = s1; p2[threadIdx.x >> 6] = s2; }
  __syncthreads();
  if (threadIdx.x == 0) {
    float S1 = p1[0] + p1[1] + p1[2] + p1[3];
    float S2 = p2[0] + p2[1] + p2[2] + p2[3];
    float num = 0.f;
    for (int t = 0; t < 96; ++t) num += mask32[b * 96 + t];
    float mean = S1 / num;
    float var = S2 / num - 2.f * mean * mean + 512.f * mean * mean;
    stats[(b * 3 + l) * 2 + 0] = mean;
    stats[(b * 3 + l) * 2 + 1] = rsqrtf(var + 1e-12f);
  }
}

__global__ void mixB_k(const void* maskp, const float* emb, const float* out0, const float* out1,
                       const float* stats, const float* ew32, void* outp) {
  const int idx = blockIdx.x * 256 + threadIdx.x;
  const int b = idx / 49152;
  const int r = idx % 49152;
  const int t = r >> 9, f = r & 511;
  float w0 = ew32[0], w1 = ew32[1], w2 = ew32[2], gm = ew32[3];
  float mx = fmaxf(w0, fmaxf(w1, w2));
  float e0 = __expf(w0 - mx), e1 = __expf(w1 - mx), e2 = __expf(w2 - mx);
  float inv = 1.f / (e0 + e1 + e2);
  float wl[3] = {e0 * inv, e1 * inv, e2 * inv};
  float acc = 0.f;
#pragma unroll
  for (int l = 0; l < 3; ++l) {
    float v = layer_val(l, b, t, f, emb, out0, out1);
    acc += wl[l] * (v - stats[(b * 3 + l) * 2]) * stats[(b * 3 + l) * 2 + 1];
  }
  acc *= gm;
  if (detect_bf(maskp)) ((__hip_bfloat16*)outp)[idx] = __float2bfloat16(acc);
  else                  ((float*)outp)[idx] = acc;
}

// ---------------- host ----------------
extern "C" void kernel_launch(void* const* d_in, const int* in_sizes, int n_in,
                              void* d_out, int out_size, void* d_ws, size_t ws_size,
                              hipStream_t stream) {
  const int*  tokens = (const int*)d_in[0];
  const void* maskp  = d_in[1];
  const void* embt   = d_in[2];
  const void* Wk     = d_in[3];
  const void* WrRaw  = d_in[4];
  const void* bias   = d_in[5];
  const void* Wp     = d_in[6];
  const void* ew     = d_in[7];
  const void* gm     = d_in[8];

  char* ws = (char*)d_ws;
  int*   ctrs   = (int*)(ws + OFF_CTRS);
  float* stats  = (float*)(ws + OFF_STATS);
  float* ew32   = (float*)(ws + OFF_EW);
  float* mask32 = (float*)(ws + OFF_MASK32);
  float* emb    = (float*)(ws + OFF_EMB);
  float* wpt    = (float*)(ws + OFF_WPT);
  float* bias32 = (float*)(ws + OFF_BIAS);
  float* xW     = (float*)(ws + OFF_XW);
  float* out0   = (float*)(ws + OFF_OUT0);
  float* out1   = (float*)(ws + OFF_OUT1);
  float* ybuf   = (float*)(ws + OFF_Y);
  float* hbuf   = (float*)(ws + OFF_H);

  hipMemsetAsync(d_ws, 0, 131072, stream);

  prep_k<0><<<1412, 256, 0, stream>>>(tokens, maskp, embt, bias, ew, gm, Wp,
                                      bias32, mask32, ew32, emb, wpt);
  prep_k<1><<<1412, 256, 0, stream>>>(tokens, maskp, embt, bias, ew, gm, Wp,
                                      bias32, mask32, ew32, emb, wpt);

  xw_gemm_k<0><<<dim3(128, 12, 2), 256, 0, stream>>>(maskp, emb, emb, Wk, bias32, xW, 0);
  xw_gemm_k<1><<<dim3(128, 12, 2), 256, 0, stream>>>(maskp, emb, emb, Wk, bias32, xW, 0);

  int l0 = 0, l1 = 1;
  {
    void* args[] = {&xW, &WrRaw, &maskp, &wpt, &mask32, &out0, &hbuf, &ybuf, &ctrs, &l0};
    hipError_t e = hipLaunchCooperativeKernel((void*)scan_kernel, dim3(256), dim3(256), args, 0, stream);
    if (e != hipSuccess)
      scan_kernel<<<256, 256, 0, stream>>>(xW, WrRaw, maskp, wpt, mask32, out0, hbuf, ybuf, ctrs, 0);
  }

  float* x_fwd = out0;
  float* x_bwd = out0 + (size_t)8 * 96 * 256;
  xw_gemm_k<0><<<dim3(128, 12, 2), 256, 0, stream>>>(maskp, x_fwd, x_bwd, Wk, bias32, xW, 1);
  xw_gemm_k<1><<<dim3(128, 12, 2), 256, 0, stream>>>(maskp, x_fwd, x_bwd, Wk, bias32, xW, 1);

  {
    void* args[] = {&xW, &WrRaw, &maskp, &wpt, &mask32, &out1, &hbuf, &ybuf, &ctrs, &l1};
    hipError_t e = hipLaunchCooperativeKernel((void*)scan_kernel, dim3(256), dim3(256), args, 0, stream);
    if (e != hipSuccess)
      scan_kernel<<<256, 256, 0, stream>>>(xW, WrRaw, maskp, wpt, mask32, out1, hbuf, ybuf, ctrs, 1);
  }

  mixA_k<<<24, 256, 0, stream>>>(emb, out0, out1, mask32, stats);
  mixB_k<<<1536, 256, 0, stream>>>(maskp, emb, out0, out1, stats, ew32, d_out);
}